// Round 7
// baseline (544.906 us; speedup 1.0000x reference)
//
#include <hip/hip_runtime.h>
#include <hip/hip_bf16.h>

typedef __attribute__((ext_vector_type(8))) short bf16x8;
typedef __attribute__((ext_vector_type(4))) float f32x4;
typedef __attribute__((ext_vector_type(8))) unsigned short u16x8;

__device__ __forceinline__ unsigned short f2bf(float f) {
  union { float f; unsigned u; } c; c.f = f;
  unsigned u = c.u;
  u = (u + 0x7FFFu + ((u >> 16) & 1u)) >> 16;   // RNE
  return (unsigned short)u;
}

__device__ __forceinline__ void gld_lds16(const void* g, void* l) {
  __builtin_amdgcn_global_load_lds(
      (__attribute__((address_space(1))) unsigned int*)g,
      (__attribute__((address_space(3))) unsigned int*)l,
      16, 0, 0);
}

// ---- conversion job j in [0,7168) ----
// [0,4096): x->x16 ; [4096,6144): K->K16 ; [6144,7168): V -> Vt (64x64 tiles)
__device__ __forceinline__ void cvt_job(
    int j, int tid, unsigned short* smem,
    const float* __restrict__ x, unsigned short* __restrict__ x16,
    const float* __restrict__ Kw, unsigned short* __restrict__ K16,
    const float* __restrict__ Vw, unsigned short* __restrict__ V16t) {
  if (j < 6144) {
    const float* in;
    unsigned short* o;
    int i;
    if (j < 4096) {
      in = x; o = x16; i = (j * 256 + tid) * 8;
    } else {
      in = Kw; o = K16; i = ((j - 4096) * 256 + tid) * 8;
    }
    const float4* p = (const float4*)(in + i);
    float4 a = p[0], bb = p[1];
    u16x8 r;
    r[0] = f2bf(a.x); r[1] = f2bf(a.y); r[2] = f2bf(a.z); r[3] = f2bf(a.w);
    r[4] = f2bf(bb.x); r[5] = f2bf(bb.y); r[6] = f2bf(bb.z); r[7] = f2bf(bb.w);
    *(u16x8*)(o + i) = r;
  } else {
    unsigned short(*t)[65] = (unsigned short(*)[65])smem;
    const int tile = j - 6144;
    const int p0 = (tile & 63) * 64;
    const int e0 = (tile >> 6) * 64;
    const int tx = tid & 63;
    const int ty = tid >> 6;
#pragma unroll
    for (int i = 0; i < 16; ++i) {
      int p = ty + i * 4;
      t[p][tx] = f2bf(Vw[(size_t)(p0 + p) * 1024 + e0 + tx]);
    }
    __syncthreads();
#pragma unroll
    for (int i = 0; i < 16; ++i) {
      int e = ty + i * 4;
      V16t[(size_t)(e0 + e) * 4096 + p0 + tx] = t[tx][e];
    }
  }
}

// ---- one NT GEMM tile: 128x128, BK=64, bf16 MFMA (m97 structure) ----
// A [M x Kd], B [N x Kd] row-major bf16.
// EPI==0: exp2(scale * A.B^T) -> Pout bf16, atomic row sums -> lsum
// EPI==1: (A.B^T) / lin[row]  -> Cout fp32
template <int EPI>
__device__ __forceinline__ void gemm_tile(
    const unsigned short* __restrict__ A, const unsigned short* __restrict__ B,
    int row0, int col0, int Kd, int N,
    unsigned short* sA, unsigned short* sB,
    unsigned short* __restrict__ Pout, float* __restrict__ lsum,
    float* __restrict__ Cout, const float* __restrict__ lin, float scale) {
  const int tid = threadIdx.x;
  const int lane = tid & 63;
  const int w = tid >> 6;
  const int wm = w >> 1;
  const int wn = w & 1;

  f32x4 acc[4][4] = {};

  // Staging: 1024 16B-chunks/tile; chunk c -> row=c>>3, slot=c&7.
  // XOR swizzle: LDS slot s of row r holds global chunk s^(r&7).
  const unsigned short* pA[4];
  const unsigned short* pB[4];
  char* ldsA[4];
  char* ldsB[4];
#pragma unroll
  for (int j = 0; j < 4; ++j) {
    int c = j * 256 + tid;
    int r = c >> 3;
    int cs = (c & 7) ^ (r & 7);
    pA[j] = A + (size_t)(row0 + r) * Kd + cs * 8;
    pB[j] = B + (size_t)(col0 + r) * Kd + cs * 8;
    int off = (j * 256 + (w << 6)) * 16;  // wave-uniform byte base
    ldsA[j] = (char*)sA + off;
    ldsB[j] = (char*)sB + off;
  }

  // Fragment reads: r = w?*64+mi*16+ml -> r&7 == ml&7, so swizzled address
  // is a per-lane base + mi*2048 immediate.
  const int q = lane >> 4;
  const int ml = lane & 15;
  const char* fA[2];
  const char* fB[2];
#pragma unroll
  for (int ks = 0; ks < 2; ++ks) {
    int cc = (ks * 4 + q) ^ (ml & 7);
    fA[ks] = (const char*)sA + (wm * 64 + ml) * 128 + cc * 16;
    fB[ks] = (const char*)sB + (wn * 64 + ml) * 128 + cc * 16;
  }

  const int kIters = Kd >> 6;
  for (int it = 0; it < kIters; ++it) {
    __syncthreads();
#pragma unroll
    for (int j = 0; j < 4; ++j) {
      gld_lds16(pA[j], ldsA[j]);
      gld_lds16(pB[j], ldsB[j]);
      pA[j] += 64;
      pB[j] += 64;
    }
    __syncthreads();
#pragma unroll
    for (int ks = 0; ks < 2; ++ks) {
      bf16x8 af[4], bfr[4];
#pragma unroll
      for (int mi = 0; mi < 4; ++mi) af[mi] = *(const bf16x8*)(fA[ks] + mi * 2048);
#pragma unroll
      for (int ni = 0; ni < 4; ++ni) bfr[ni] = *(const bf16x8*)(fB[ks] + ni * 2048);
#pragma unroll
      for (int mi = 0; mi < 4; ++mi)
#pragma unroll
        for (int ni = 0; ni < 4; ++ni)
          acc[mi][ni] = __builtin_amdgcn_mfma_f32_16x16x32_bf16(
              af[mi], bfr[ni], acc[mi][ni], 0, 0, 0);
    }
  }

  if constexpr (EPI == 0) {
#pragma unroll
    for (int mi = 0; mi < 4; ++mi) {
#pragma unroll
      for (int j = 0; j < 4; ++j) {
        int gr = row0 + wm * 64 + mi * 16 + q * 4 + j;
        float rsum = 0.f;
#pragma unroll
        for (int ni = 0; ni < 4; ++ni) {
          int gc = col0 + wn * 64 + ni * 16 + ml;
          float p = exp2f(acc[mi][ni][j] * scale);  // scale includes log2(e)
          rsum += p;
          Pout[(size_t)gr * N + gc] = f2bf(p);
        }
        rsum += __shfl_xor(rsum, 1);
        rsum += __shfl_xor(rsum, 2);
        rsum += __shfl_xor(rsum, 4);
        rsum += __shfl_xor(rsum, 8);
        if (ml == 0) atomicAdd(&lsum[gr], rsum);
      }
    }
  } else {
#pragma unroll
    for (int mi = 0; mi < 4; ++mi) {
#pragma unroll
      for (int j = 0; j < 4; ++j) {
        int gr = row0 + wm * 64 + mi * 16 + q * 4 + j;
        float rl = 1.0f / lin[gr];
#pragma unroll
        for (int ni = 0; ni < 4; ++ni) {
          int gc = col0 + wn * 64 + ni * 16 + ml;
          Cout[(size_t)gr * N + gc] = acc[mi][ni][j] * rl;
        }
      }
    }
  }
}

// ---------------- kernel 1: conversions + flag init ----------------
__global__ void cvt_all_k(const float* __restrict__ x, unsigned short* __restrict__ x16,
                          const float* __restrict__ Kw, unsigned short* __restrict__ K16,
                          const float* __restrict__ Vw, unsigned short* __restrict__ V16t,
                          float* __restrict__ lsum, unsigned int* __restrict__ ctr) {
  __shared__ __align__(16) unsigned short smem[64 * 65];
  if (blockIdx.x < 32) lsum[blockIdx.x * 256 + threadIdx.x] = 0.f;
  if (blockIdx.x == 32 && threadIdx.x < 64) ctr[threadIdx.x] = 0u;
  cvt_job(blockIdx.x, threadIdx.x, smem, x, x16, Kw, K16, Vw, V16t);
}

// ---------------- kernel 2: merged GEMM1 + GEMM2 (m-strip interleaved) -----
// 2560 blocks; strip m = b/40, r = b%40.
//   r in [0,32):  GEMM1 tile (m, n=r); after epilogue one agent-scope RELEASE
//                 increment of ctr[m].
//   r in [32,40): GEMM2 tile (m, n=r-32); ACQUIRE-spin until ctr[m]==32.
// NO min-waves clamp (round 6's (256,4) forced VGPR 64 -> scratch spill,
// +40 MB FETCH/WRITE, MfmaUtil 14%). At VGPR 80 + 64 acc -> 3 blocks/CU:
// 768 resident slots > 512 possible spinners + 256 producer slots, so
// producers always progress regardless of dispatch order (G16-safe).
__global__ __launch_bounds__(256) void gemm_fused(
    const unsigned short* __restrict__ x16, const unsigned short* __restrict__ K16,
    const unsigned short* __restrict__ V16t, unsigned short* __restrict__ P16,
    float* __restrict__ lsum, float* __restrict__ out,
    unsigned int* __restrict__ ctr) {
  __shared__ __align__(16) unsigned short sA[128 * 64];
  __shared__ __align__(16) unsigned short sB[128 * 64];
  const int b = blockIdx.x;
  const int m = b / 40;
  const int r = b - m * 40;

  if (r < 32) {
    const float sc = 0.03125f * 1.44269504088896340736f;  // (1/32)*log2e
    gemm_tile<0>(x16, K16, m * 128, r * 128, 1024, 4096, sA, sB,
                 P16, lsum, nullptr, nullptr, sc);
    // Barrier drains all waves' stores (compiler emits vmcnt(0) before
    // s_barrier), then one release-increment publishes the strip.
    __syncthreads();
    if (threadIdx.x == 0)
      __hip_atomic_fetch_add(&ctr[m], 1u, __ATOMIC_RELEASE,
                             __HIP_MEMORY_SCOPE_AGENT);
  } else {
    const int n = r - 32;
    if (threadIdx.x == 0) {
      while (__hip_atomic_load(&ctr[m], __ATOMIC_ACQUIRE,
                               __HIP_MEMORY_SCOPE_AGENT) < 32u)
        __builtin_amdgcn_s_sleep(16);
    }
    __syncthreads();  // all threads wait behind the acquire
    gemm_tile<1>(P16, V16t, m * 128, n * 128, 4096, 1024, sA, sB,
                 nullptr, nullptr, out, lsum, 1.0f);
  }
}

extern "C" void kernel_launch(void* const* d_in, const int* in_sizes, int n_in,
                              void* d_out, int out_size, void* d_ws,
                              size_t ws_size, hipStream_t stream) {
  const float* x = (const float*)d_in[0];   // [8192,1024]
  const float* Kw = (const float*)d_in[1];  // [4096,1024]
  const float* Vw = (const float*)d_in[2];  // [4096,1024]
  float* out = (float*)d_out;               // [8192,1024]
  char* ws = (char*)d_ws;

  unsigned short* x16  = (unsigned short*)(ws);                        // 16 MB
  unsigned short* K16  = (unsigned short*)(ws + (16u << 20));          //  8 MB
  unsigned short* V16t = (unsigned short*)(ws + (24u << 20));          //  8 MB
  float*          lsum = (float*)(ws + (32u << 20));                   // 32 KB
  unsigned int*   ctr  = (unsigned int*)(ws + (32u << 20) + 32768);    // 256 B
  unsigned short* P16  = (unsigned short*)(ws + (33u << 20));          // 64 MB

  cvt_all_k<<<7168, 256, 0, stream>>>(x, x16, Kw, K16, Vw, V16t, lsum, ctr);
  gemm_fused<<<2560, 256, 0, stream>>>(x16, K16, V16t, P16, lsum, out, ctr);
}

// Round 8
// 296.191 us; speedup vs baseline: 1.8397x; 1.8397x over previous
//
#include <hip/hip_runtime.h>
#include <hip/hip_bf16.h>

typedef __attribute__((ext_vector_type(8))) short bf16x8;
typedef __attribute__((ext_vector_type(16))) float f32x16;
typedef __attribute__((ext_vector_type(8))) unsigned short u16x8;

__device__ __forceinline__ unsigned short f2bf(float f) {
  union { float f; unsigned u; } c; c.f = f;
  unsigned u = c.u;
  u = (u + 0x7FFFu + ((u >> 16) & 1u)) >> 16;   // RNE
  return (unsigned short)u;
}

__device__ __forceinline__ void gld_lds16(const void* g, void* l) {
  __builtin_amdgcn_global_load_lds(
      (__attribute__((address_space(1))) unsigned int*)g,
      (__attribute__((address_space(3))) unsigned int*)l,
      16, 0, 0);
}

// ---- conversion job j in [0,7168) ----
// [0,4096): x->x16 ; [4096,6144): K->K16 ; [6144,7168): V -> Vt (64x64 tiles)
__device__ __forceinline__ void cvt_job(
    int j, int tid, unsigned short* smem,
    const float* __restrict__ x, unsigned short* __restrict__ x16,
    const float* __restrict__ Kw, unsigned short* __restrict__ K16,
    const float* __restrict__ Vw, unsigned short* __restrict__ V16t) {
  if (j < 6144) {
    const float* in;
    unsigned short* o;
    int i;
    if (j < 4096) {
      in = x; o = x16; i = (j * 256 + tid) * 8;
    } else {
      in = Kw; o = K16; i = ((j - 4096) * 256 + tid) * 8;
    }
    const float4* p = (const float4*)(in + i);
    float4 a = p[0], bb = p[1];
    u16x8 r;
    r[0] = f2bf(a.x); r[1] = f2bf(a.y); r[2] = f2bf(a.z); r[3] = f2bf(a.w);
    r[4] = f2bf(bb.x); r[5] = f2bf(bb.y); r[6] = f2bf(bb.z); r[7] = f2bf(bb.w);
    *(u16x8*)(o + i) = r;
  } else {
    unsigned short(*t)[65] = (unsigned short(*)[65])smem;
    const int tile = j - 6144;
    const int p0 = (tile & 63) * 64;
    const int e0 = (tile >> 6) * 64;
    const int tx = tid & 63;
    const int ty = tid >> 6;
#pragma unroll
    for (int i = 0; i < 16; ++i) {
      int p = ty + i * 4;
      t[p][tx] = f2bf(Vw[(size_t)(p0 + p) * 1024 + e0 + tx]);
    }
    __syncthreads();
#pragma unroll
    for (int i = 0; i < 16; ++i) {
      int e = ty + i * 4;
      V16t[(size_t)(e0 + e) * 4096 + p0 + tx] = t[tx][e];
    }
  }
}

// ---- one NT GEMM tile: 128x128, BK=64, 32x32x16 bf16 MFMA ----
// A [M x Kd], B [N x Kd] row-major bf16.
// Wave (wm,wn) owns a 64x64 quadrant = 2x2 subtiles of 32x32.
// A/B frag: elem [m|n = lane&31][k = (lane>>5)*8 + j]  (analogy of the
// verified 16x16x32 mapping). C/D: col=lane&31,
// row=(reg&3)+8*(reg>>2)+4*(lane>>5)  [m74/m101 verified].
// EPI==0: exp2(scale * A.B^T) -> Pout bf16, atomic row sums -> lsum
// EPI==1: (A.B^T) / lin[row]  -> Cout fp32
template <int EPI>
__device__ __forceinline__ void gemm_tile(
    const unsigned short* __restrict__ A, const unsigned short* __restrict__ B,
    int row0, int col0, int Kd, int N,
    unsigned short* sA, unsigned short* sB,
    unsigned short* __restrict__ Pout, float* __restrict__ lsum,
    float* __restrict__ Cout, const float* __restrict__ lin, float scale) {
  const int tid = threadIdx.x;
  const int lane = tid & 63;
  const int w = tid >> 6;
  const int wm = w >> 1;
  const int wn = w & 1;

  f32x16 acc[2][2] = {};  // [sm][sn]

  // Staging: 1024 16B-chunks/tile; chunk c -> row=c>>3, slot=c&7.
  // XOR swizzle: LDS slot s of row r holds global chunk s^(r&7).
  const unsigned short* pA[4];
  const unsigned short* pB[4];
  char* ldsA[4];
  char* ldsB[4];
#pragma unroll
  for (int j = 0; j < 4; ++j) {
    int c = j * 256 + tid;
    int r = c >> 3;
    int cs = (c & 7) ^ (r & 7);
    pA[j] = A + (size_t)(row0 + r) * Kd + cs * 8;
    pB[j] = B + (size_t)(col0 + r) * Kd + cs * 8;
    int off = (j * 256 + (w << 6)) * 16;  // wave-uniform byte base
    ldsA[j] = (char*)sA + off;
    ldsB[j] = (char*)sB + off;
  }

  // Fragment pointers: row r = wm*64 + sm*32 + (lane&31) -> r&7 == lane&7,
  // so swizzled addr = base[kstep] + sm*4096 (imm).
  const int l31 = lane & 31;
  const int ls5 = lane >> 5;
  const int l7 = lane & 7;
  const char* fA[4];
  const char* fB[4];
#pragma unroll
  for (int ks = 0; ks < 4; ++ks) {
    int swz = ((ks * 2 + ls5) ^ l7) * 16;
    fA[ks] = (const char*)sA + (wm * 64 + l31) * 128 + swz;
    fB[ks] = (const char*)sB + (wn * 64 + l31) * 128 + swz;
  }

  const int kIters = Kd >> 6;
  for (int it = 0; it < kIters; ++it) {
    __syncthreads();
#pragma unroll
    for (int j = 0; j < 4; ++j) {
      gld_lds16(pA[j], ldsA[j]);
      gld_lds16(pB[j], ldsB[j]);
      pA[j] += 64;
      pB[j] += 64;
    }
    __syncthreads();
#pragma unroll
    for (int ks = 0; ks < 4; ++ks) {
      bf16x8 a0 = *(const bf16x8*)(fA[ks]);
      bf16x8 a1 = *(const bf16x8*)(fA[ks] + 32 * 128);
      bf16x8 b0 = *(const bf16x8*)(fB[ks]);
      bf16x8 b1 = *(const bf16x8*)(fB[ks] + 32 * 128);
      acc[0][0] = __builtin_amdgcn_mfma_f32_32x32x16_bf16(a0, b0, acc[0][0], 0, 0, 0);
      acc[0][1] = __builtin_amdgcn_mfma_f32_32x32x16_bf16(a0, b1, acc[0][1], 0, 0, 0);
      acc[1][0] = __builtin_amdgcn_mfma_f32_32x32x16_bf16(a1, b0, acc[1][0], 0, 0, 0);
      acc[1][1] = __builtin_amdgcn_mfma_f32_32x32x16_bf16(a1, b1, acc[1][1], 0, 0, 0);
    }
  }

  // C/D: col = lane&31 (+sn*32), row = (reg&3)+8*(reg>>2)+4*ls5 (+sm*32)
  const int gc0 = col0 + wn * 64 + l31;
  if constexpr (EPI == 0) {
#pragma unroll
    for (int sm = 0; sm < 2; ++sm) {
#pragma unroll
      for (int reg = 0; reg < 16; ++reg) {
        int gr = row0 + wm * 64 + sm * 32 + (reg & 3) + 8 * (reg >> 2) + 4 * ls5;
        float p0 = exp2f(acc[sm][0][reg] * scale);  // scale includes log2(e)
        float p1 = exp2f(acc[sm][1][reg] * scale);
        Pout[(size_t)gr * N + gc0] = f2bf(p0);
        Pout[(size_t)gr * N + gc0 + 32] = f2bf(p1);
        float rs = p0 + p1;
        rs += __shfl_xor(rs, 1);
        rs += __shfl_xor(rs, 2);
        rs += __shfl_xor(rs, 4);
        rs += __shfl_xor(rs, 8);
        rs += __shfl_xor(rs, 16);
        if (l31 == 0) atomicAdd(&lsum[gr], rs);
      }
    }
  } else {
#pragma unroll
    for (int sm = 0; sm < 2; ++sm) {
#pragma unroll
      for (int reg = 0; reg < 16; ++reg) {
        int gr = row0 + wm * 64 + sm * 32 + (reg & 3) + 8 * (reg >> 2) + 4 * ls5;
        float rl = 1.0f / lin[gr];
        Cout[(size_t)gr * N + gc0] = acc[sm][0][reg] * rl;
        Cout[(size_t)gr * N + gc0 + 32] = acc[sm][1][reg] * rl;
      }
    }
  }
}

// ---------------- kernel 1: conversions + lsum zero ----------------
__global__ void cvt_all_k(const float* __restrict__ x, unsigned short* __restrict__ x16,
                          const float* __restrict__ Kw, unsigned short* __restrict__ K16,
                          const float* __restrict__ Vw, unsigned short* __restrict__ V16t,
                          float* __restrict__ lsum) {
  __shared__ __align__(16) unsigned short smem[64 * 65];
  if (blockIdx.x < 32) lsum[blockIdx.x * 256 + threadIdx.x] = 0.f;
  cvt_job(blockIdx.x, threadIdx.x, smem, x, x16, Kw, K16, Vw, V16t);
}

// ---------------- kernel 2: GEMM1 ----------------
__global__ __launch_bounds__(256) void gemm1_k(
    const unsigned short* __restrict__ A, const unsigned short* __restrict__ B,
    unsigned short* __restrict__ P, float* __restrict__ lsum, float scale) {
  __shared__ __align__(16) unsigned short sA[128 * 64];
  __shared__ __align__(16) unsigned short sB[128 * 64];
  gemm_tile<0>(A, B, blockIdx.y * 128, blockIdx.x * 128, 1024, 4096, sA, sB,
               P, lsum, nullptr, nullptr, scale);
}

// ---------------- kernel 3: GEMM2 (XCD-swizzled 1D grid) ----------------
__global__ __launch_bounds__(256) void gemm2_k(
    const unsigned short* __restrict__ A, const unsigned short* __restrict__ B,
    float* __restrict__ out, const float* __restrict__ lsum) {
  __shared__ __align__(16) unsigned short sA[128 * 64];
  __shared__ __align__(16) unsigned short sB[128 * 64];
  const int bid = blockIdx.x;
  const int row0 = (((bid >> 6) << 3) | (bid & 7)) * 128;
  const int col0 = ((bid >> 3) & 7) * 128;
  gemm_tile<1>(A, B, row0, col0, 4096, 1024, sA, sB,
               nullptr, nullptr, out, lsum, 1.0f);
}

extern "C" void kernel_launch(void* const* d_in, const int* in_sizes, int n_in,
                              void* d_out, int out_size, void* d_ws,
                              size_t ws_size, hipStream_t stream) {
  const float* x = (const float*)d_in[0];   // [8192,1024]
  const float* Kw = (const float*)d_in[1];  // [4096,1024]
  const float* Vw = (const float*)d_in[2];  // [4096,1024]
  float* out = (float*)d_out;               // [8192,1024]
  char* ws = (char*)d_ws;

  unsigned short* x16  = (unsigned short*)(ws);                   // 16 MB
  unsigned short* K16  = (unsigned short*)(ws + (16u << 20));     //  8 MB
  unsigned short* V16t = (unsigned short*)(ws + (24u << 20));     //  8 MB
  float*          lsum = (float*)(ws + (32u << 20));              // 32 KB
  unsigned short* P16  = (unsigned short*)(ws + (33u << 20));     // 64 MB

  const float sc = 0.03125f * 1.44269504088896340736f;  // (1/32)*log2e

  cvt_all_k<<<7168, 256, 0, stream>>>(x, x16, Kw, K16, Vw, V16t, lsum);
  gemm1_k<<<dim3(32, 64), 256, 0, stream>>>(x16, K16, P16, lsum, sc);
  gemm2_k<<<512, 256, 0, stream>>>(P16, V16t, out, lsum);
}